// Round 1
// 154.773 us; speedup vs baseline: 1.1269x; 1.1269x over previous
//
#include <hip/hip_runtime.h>
#include <math.h>

typedef _Float16 h8 __attribute__((ext_vector_type(8)));
typedef _Float16 h4 __attribute__((ext_vector_type(4)));
typedef float    f4 __attribute__((ext_vector_type(4)));

#define SAMPLES 64
#define HIDDEN  256

// d_ws layout (units: _Float16). Weights pre-split hi/lo, fragment order:
//   ws[((kg*16 + ct)*64 + ln)*8 + j] = W[kg*32 + ((ln>>4)<<3) + j][ct*16 + (ln&15)]
#define OFF_W0HI 0            // [2][16][64][8]  = 16384 halfs
#define OFF_W0LO 16384
#define OFF_W1HI 32768        // [8][16][64][8]  = 65536
#define OFF_W1LO 98304
#define OFF_W2HI 163840
#define OFF_W2LO 229376
#define OFF_W3HI 294912       // [8][64][8] = 4096 (W3 cols padded 4->16)
#define OFF_W3LO 299008

// One fragment tile per wave: 296 waves over 74 blocks. Loads hit L2 in
// 64B segments; stores are fully coalesced 16B/lane.
__launch_bounds__(256)
__global__ void prep_weights(const float* __restrict__ W0,
                             const float* __restrict__ W1,
                             const float* __restrict__ W2,
                             const float* __restrict__ W3,
                             _Float16* __restrict__ ws)
{
    const int ln = threadIdx.x & 63;
    const int t  = blockIdx.x * 4 + (threadIdx.x >> 6);   // tile id 0..295
    if (t >= 296) return;

    const float* src; int hioff, looff, kg, ct, kmax, colmax, wide;
    if (t < 32)       { src=W0; hioff=OFF_W0HI; looff=OFF_W0LO; kg=t>>4;        ct=t&15;        kmax=63;  colmax=256; wide=1; }
    else if (t < 160) { int u=t-32;  src=W1; hioff=OFF_W1HI; looff=OFF_W1LO; kg=u>>4; ct=u&15; kmax=256; colmax=256; wide=1; }
    else if (t < 288) { int u=t-160; src=W2; hioff=OFF_W2HI; looff=OFF_W2LO; kg=u>>4; ct=u&15; kmax=256; colmax=256; wide=1; }
    else              { int u=t-288; src=W3; hioff=OFF_W3HI; looff=OFF_W3LO; kg=u;    ct=0;    kmax=256; colmax=4;   wide=0; }

    const int col = ct*16 + (ln & 15);
    const int k0  = kg*32 + ((ln >> 4) << 3);
    h8 vh, vl;
#pragma unroll
    for (int j = 0; j < 8; ++j) {
        int k = k0 + j;
        float v = (k < kmax && col < colmax) ? src[k*colmax + col] : 0.0f;
        _Float16 h = (_Float16)v;
        vh[j] = h;
        vl[j] = (_Float16)(v - (float)h);
    }
    int di = wide ? ((kg*16 + ct)*64 + ln) : (kg*64 + ln);
    ((h8*)(ws + hioff))[di] = vh;
    ((h8*)(ws + looff))[di] = vl;
}

// 2-term split-GEMM: weights stay hi/lo (exact to ~2^-22), activations are
// plain f16. Error per layer ~ sqrt(K)*|W|rms*|h|*2^-12 ~ 3e-5 — the 3rd
// (alo*bhi) term of the previous 3-MFMA scheme bought ~10x precision we do
// not need at the harness tolerance, at +50% MFMA cost.
__device__ __forceinline__ f4 mfma2(h8 ahi, h8 alo, h8 b, f4 c)
{
    c = __builtin_amdgcn_mfma_f32_16x16x32_f16(alo, b, c, 0, 0, 0);   // small term first
    c = __builtin_amdgcn_mfma_f32_16x16x32_f16(ahi, b, c, 0, 0, 0);
    return c;
}

// Swapped orientation: D[ch][samp] = W^T @ H^T. Wave wv owns channels
// wv*32..+31 (cht=0,1) x ALL 64 samples (st=0..3): 4 global h8 loads/kg
// (explicitly prefetched one kg ahead), 4 ds_read_b128/kg, 16 MFMA/kg.
// B is a single f16 array [kg][4st][64ln][8], updated in place (2 barriers).
template<int NKG>
__device__ __forceinline__ void dense_layer(const _Float16* __restrict__ Whi,
                                            const _Float16* __restrict__ Wlo,
                                            const float*    __restrict__ bias,
                                            _Float16* B, int wv, int lane)
{
    const int q  = lane >> 4;
    const int jl = lane & 15;
    f4 acc[2][4];
#pragma unroll
    for (int cht = 0; cht < 2; ++cht) {
        f4 bb = ((const f4*)bias)[wv*8 + cht*4 + q];   // acc row r -> ch q*4+r
#pragma unroll
        for (int st = 0; st < 4; ++st) acc[cht][st] = bb;
    }
    const h8* wh = (const h8*)Whi;
    const h8* wl = (const h8*)Wlo;
    const h8* bp = (const h8*)B;

    h8 cah[2], cal[2];
#pragma unroll
    for (int cht = 0; cht < 2; ++cht) {            // kg=0 prefetch
        int wi = (wv*2 + cht)*64 + lane;
        cah[cht] = wh[wi];
        cal[cht] = wl[wi];
    }

#pragma unroll
    for (int kg = 0; kg < NKG; ++kg) {
        h8 nah[2], nal[2];
        int kn = (kg + 1 < NKG) ? kg + 1 : kg;     // harmless re-load on last iter
#pragma unroll
        for (int cht = 0; cht < 2; ++cht) {
            int wi = (kn*16 + wv*2 + cht)*64 + lane;
            nah[cht] = wh[wi];
            nal[cht] = wl[wi];
        }
        h8 bh[4];
#pragma unroll
        for (int st = 0; st < 4; ++st)
            bh[st] = bp[(kg*4 + st)*64 + lane];    // ds_read_b128, conflict-free
#pragma unroll
        for (int cht = 0; cht < 2; ++cht)
#pragma unroll
            for (int st = 0; st < 4; ++st)
                acc[cht][st] = mfma2(cah[cht], cal[cht], bh[st], acc[cht][st]);
        cah[0] = nah[0]; cah[1] = nah[1];
        cal[0] = nal[0]; cal[1] = nal[1];
    }

    __syncthreads();   // all waves done reading before in-place overwrite

    // relu + f16 round into next layer's B-frag layout.
    // ch = wv*32 + cht*16 + q*4 + r  ->  k' bits: kg'=wv, ln'hi=cht*2+(q>>1),
    // j' = (q&1)*4 + r  ->  one ds_write_b64 per (cht,st).
#pragma unroll
    for (int cht = 0; cht < 2; ++cht) {
        int lnp = jl + 16*(cht*2 + (q >> 1));
        int jb  = (q & 1)*4;
#pragma unroll
        for (int st = 0; st < 4; ++st) {
            h4 vh;
#pragma unroll
            for (int r = 0; r < 4; ++r)
                vh[r] = (_Float16)fmaxf(acc[cht][st][r], 0.0f);
            *(h4*)(B + ((wv*4 + st)*64 + lnp)*8 + jb) = vh;
        }
    }
    __syncthreads();
}

// (512,2): 2nd arg = min BLOCKS/CU on hipcc (r4 evidence: (512,4) -> 64-VGPR
// cap -> scratch spill disaster). LDS is now 33 KB -> up to 4 blocks/CU
// (32 waves) if actual VGPR use stays <=64; 3 blocks/CU otherwise.
__launch_bounds__(512, 2)
__global__ void nerf_fused(const float* __restrict__ origins,
                           const float* __restrict__ dirs,
                           const float* __restrict__ nearp,
                           const float* __restrict__ farp,
                           const float* __restrict__ b0,
                           const float* __restrict__ b1,
                           const float* __restrict__ b2,
                           const float* __restrict__ b3,
                           const _Float16* __restrict__ ws,
                           float* __restrict__ out)
{
    extern __shared__ _Float16 sm[];
    _Float16* B = sm;                       // [kg][4st][64ln][8] = 16384 halfs = 32 KB
    float* headv = (float*)(sm + 16384);    // [64 samp][4] f32 = 1 KB

    const int tid  = threadIdx.x;
    const int wv   = tid >> 6;
    const int lane = tid & 63;
    const int ray  = blockIdx.x;

    const float near = nearp[0];
    const float far  = farp[0];
    const float step = (far - near) * (1.0f / 64.0f);

    const float ox = origins[ray*3+0], oy = origins[ray*3+1], oz = origins[ray*3+2];
    const float dx = dirs[ray*3+0],    dy = dirs[ray*3+1],    dz = dirs[ray*3+2];

    // ---- PE directly into B-frag layout (K padded 63->64): one h8 per thread
    {
        int b  = tid;                    // = (kg*4+st)*64 + ln
        int ln = b & 63;
        int sample = ((b >> 6) & 3)*16 + (ln & 15);
        int k0 = (b >> 8)*32 + ((ln >> 4) << 3);
        float mid = (near + (float)sample*step) + (near + (float)(sample+1)*step)*0.5f;
        float c3[3] = { ox + mid*dx, oy + mid*dy, oz + mid*dz };
        h8 vh;
#pragma unroll
        for (int j = 0; j < 8; ++j) {
            int k = k0 + j;
            float v;
            if (k < 3) v = c3[k];
            else if (k < 63) {
                int t = k - 3, l = t/6, r = t%6, d = r%3;
                float a = c3[d] * (float)(1 << l);
                v = (r < 3) ? sinf(a) : cosf(a);
            } else v = 0.0f;
            vh[j] = (_Float16)v;
        }
        ((h8*)B)[b] = vh;
    }
    __syncthreads();

    dense_layer<2>(ws+OFF_W0HI, ws+OFF_W0LO, b0, B, wv, lane);
    dense_layer<8>(ws+OFF_W1HI, ws+OFF_W1LO, b1, B, wv, lane);
    dense_layer<8>(ws+OFF_W2HI, ws+OFF_W2LO, b2, B, wv, lane);

    // ---- head: D[16pad ch][64 samp], K split across 8 waves (kg = wv)
    f4 hacc[4];
#pragma unroll
    for (int st = 0; st < 4; ++st) hacc[st] = (f4){0.f, 0.f, 0.f, 0.f};
    {
        h8 ah = ((const h8*)(ws+OFF_W3HI))[wv*64 + lane];
        h8 al = ((const h8*)(ws+OFF_W3LO))[wv*64 + lane];
        const h8* bp = (const h8*)B;
#pragma unroll
        for (int st = 0; st < 4; ++st)
            hacc[st] = mfma2(ah, al, bp[(wv*4 + st)*64 + lane], hacc[st]);
    }
    __syncthreads();                       // B reads done -> safe to alias

    f4* part = (f4*)sm;                    // [wv][st][lane] f4 = 32 KB (B region)
#pragma unroll
    for (int st = 0; st < 4; ++st) part[(wv*4 + st)*64 + lane] = hacc[st];
    __syncthreads();

    if (tid < 256) {
        int st = tid >> 6, l = tid & 63;
        f4 s = part[(0*4 + st)*64 + l];
#pragma unroll
        for (int w = 1; w < 8; ++w) s += part[(w*4 + st)*64 + l];
        int q = l >> 4, jl = l & 15;
        if (q == 0) {                      // rows 0..3 = the real 4 channels
            s += *(const f4*)b3;
            ((f4*)headv)[st*16 + jl] = s;  // [sample] -> (r,g,b,sigma)
        }
    }
    __syncthreads();

    // ---- compositing: wave 0, lane = sample
    if (tid < 64) {
        f4 f = ((const f4*)headv)[tid];
        const int p = tid;
        float sigma = fmaxf(f[3], 0.0f);
        float delta = (near + (float)(p + 1)*step) - (near + (float)p*step);
        float alpha = 1.0f - expf(-sigma * delta);
        float om    = 1.0f - alpha;

        float prod = om;
#pragma unroll
        for (int off = 1; off < 64; off <<= 1) {
            float v = __shfl_up(prod, off, 64);
            if (p >= off) prod *= v;
        }
        float T = __shfl_up(prod, 1, 64);
        if (p == 0) T = 1.0f;
        float w = T * alpha;

        float r  = w * (1.0f / (1.0f + expf(-f[0])));
        float g  = w * (1.0f / (1.0f + expf(-f[1])));
        float bb = w * (1.0f / (1.0f + expf(-f[2])));
#pragma unroll
        for (int off = 32; off > 0; off >>= 1) {
            r  += __shfl_down(r,  off, 64);
            g  += __shfl_down(g,  off, 64);
            bb += __shfl_down(bb, off, 64);
        }
        if (p == 0) {
            out[ray*3 + 0] = r;
            out[ray*3 + 1] = g;
            out[ray*3 + 2] = bb;
        }
    }
}

extern "C" void kernel_launch(void* const* d_in, const int* in_sizes, int n_in,
                              void* d_out, int out_size, void* d_ws, size_t ws_size,
                              hipStream_t stream) {
    const float* origins = (const float*)d_in[0];
    const float* dirs    = (const float*)d_in[1];
    const float* nearp   = (const float*)d_in[2];
    const float* farp    = (const float*)d_in[3];
    const float* W0      = (const float*)d_in[4];
    const float* b0      = (const float*)d_in[5];
    const float* W1      = (const float*)d_in[6];
    const float* b1      = (const float*)d_in[7];
    const float* W2      = (const float*)d_in[8];
    const float* b2      = (const float*)d_in[9];
    const float* W3      = (const float*)d_in[10];
    const float* b3      = (const float*)d_in[11];
    float* out           = (float*)d_out;
    _Float16* ws         = (_Float16*)d_ws;

    const int nrays = in_sizes[0] / 3;

    prep_weights<<<dim3(74), dim3(256), 0, stream>>>(W0, W1, W2, W3, ws);

    const size_t shmem = 16384 * sizeof(_Float16) + 64 * sizeof(f4);   // 33 KiB
    hipFuncSetAttribute(reinterpret_cast<const void*>(nerf_fused),
                        hipFuncAttributeMaxDynamicSharedMemorySize,
                        (int)shmem);
    nerf_fused<<<dim3(nrays), dim3(512), shmem, stream>>>(
        origins, dirs, nearp, farp, b0, b1, b2, b3, ws, out);
}

// Round 2
// 140.237 us; speedup vs baseline: 1.2437x; 1.1037x over previous
//
#include <hip/hip_runtime.h>
#include <math.h>

typedef _Float16 h8 __attribute__((ext_vector_type(8)));
typedef _Float16 h4 __attribute__((ext_vector_type(4)));
typedef float    f4 __attribute__((ext_vector_type(4)));

#define SAMPLES 64
#define HIDDEN  256

// d_ws layout (units: _Float16). Weights plain f16 (RNE), fragment order:
//   ws[((kg*16 + ct)*64 + ln)*8 + j] = W[kg*32 + ((ln>>4)<<3) + j][ct*16 + (ln&15)]
#define OFF_W0 0            // [2][16][64][8]  = 16384 halfs
#define OFF_W1 16384        // [8][16][64][8]  = 65536
#define OFF_W2 81920
#define OFF_W3 147456       // [8][64][8] = 4096 (W3 cols padded 4->16)

// One fragment tile per wave: 296 waves over 74 blocks.
__launch_bounds__(256)
__global__ void prep_weights(const float* __restrict__ W0,
                             const float* __restrict__ W1,
                             const float* __restrict__ W2,
                             const float* __restrict__ W3,
                             _Float16* __restrict__ ws)
{
    const int ln = threadIdx.x & 63;
    const int t  = blockIdx.x * 4 + (threadIdx.x >> 6);   // tile id 0..295
    if (t >= 296) return;

    const float* src; int off, kg, ct, kmax, colmax, wide;
    if (t < 32)       { src=W0; off=OFF_W0; kg=t>>4;        ct=t&15;        kmax=63;  colmax=256; wide=1; }
    else if (t < 160) { int u=t-32;  src=W1; off=OFF_W1; kg=u>>4; ct=u&15; kmax=256; colmax=256; wide=1; }
    else if (t < 288) { int u=t-160; src=W2; off=OFF_W2; kg=u>>4; ct=u&15; kmax=256; colmax=256; wide=1; }
    else              { int u=t-288; src=W3; off=OFF_W3; kg=u;    ct=0;    kmax=256; colmax=4;   wide=0; }

    const int col = ct*16 + (ln & 15);
    const int k0  = kg*32 + ((ln >> 4) << 3);
    h8 vh;
#pragma unroll
    for (int j = 0; j < 8; ++j) {
        int k = k0 + j;
        float v = (k < kmax && col < colmax) ? src[k*colmax + col] : 0.0f;
        vh[j] = (_Float16)v;   // RNE
    }
    int di = wide ? ((kg*16 + ct)*64 + ln) : (kg*64 + ln);
    ((h8*)(ws + off))[di] = vh;
}

// Swapped orientation, TWO rays per block: D[ch][samp] = W^T @ H^T.
// Wave wv owns channels wv*32..+31 (cht=0,1) x 128 samples (st=0..7:
// st = ray*4 + sampleTile). Per kg: 2 global h8 loads (prefetched one kg
// ahead), 8 ds_read_b128, 16 MFMA -> weight L2 traffic amortized over 2 rays.
// B is a single f16 array [kg][8st][64ln][8], updated in place (2 barriers).
template<int NKG>
__device__ __forceinline__ void dense_layer(const _Float16* __restrict__ W,
                                            const float*    __restrict__ bias,
                                            _Float16* B, int wv, int lane)
{
    const int q  = lane >> 4;
    const int jl = lane & 15;
    f4 acc[2][8];
#pragma unroll
    for (int cht = 0; cht < 2; ++cht) {
        f4 bb = ((const f4*)bias)[wv*8 + cht*4 + q];   // acc row r -> ch q*4+r
#pragma unroll
        for (int st = 0; st < 8; ++st) acc[cht][st] = bb;
    }
    const h8* wp = (const h8*)W;
    const h8* bp = (const h8*)B;

    h8 ca[2];
#pragma unroll
    for (int cht = 0; cht < 2; ++cht)              // kg=0 prefetch
        ca[cht] = wp[(wv*2 + cht)*64 + lane];

#pragma unroll
    for (int kg = 0; kg < NKG; ++kg) {
        h8 na[2];
        int kn = (kg + 1 < NKG) ? kg + 1 : kg;     // harmless re-load on last iter
#pragma unroll
        for (int cht = 0; cht < 2; ++cht)
            na[cht] = wp[(kn*16 + wv*2 + cht)*64 + lane];
#pragma unroll
        for (int st = 0; st < 8; ++st) {
            h8 bh = bp[(kg*8 + st)*64 + lane];     // ds_read_b128, conflict-free
            acc[0][st] = __builtin_amdgcn_mfma_f32_16x16x32_f16(ca[0], bh, acc[0][st], 0, 0, 0);
            acc[1][st] = __builtin_amdgcn_mfma_f32_16x16x32_f16(ca[1], bh, acc[1][st], 0, 0, 0);
        }
        ca[0] = na[0]; ca[1] = na[1];
    }

    __syncthreads();   // all waves done reading before in-place overwrite

    // relu + f16 round into next layer's B-frag layout.
    // ch = wv*32 + cht*16 + q*4 + r  ->  kg'=wv, ln'hi = cht*2+(q>>1),
    // j' = (q&1)*4 + r; st carries (ray, sampleTile) through unchanged.
#pragma unroll
    for (int cht = 0; cht < 2; ++cht) {
        int lnp = jl + 16*(cht*2 + (q >> 1));
        int jb  = (q & 1)*4;
#pragma unroll
        for (int st = 0; st < 8; ++st) {
            h4 vh;
#pragma unroll
            for (int r = 0; r < 4; ++r)
                vh[r] = (_Float16)fmaxf(acc[cht][st][r], 0.0f);
            *(h4*)(B + ((wv*8 + st)*64 + lnp)*8 + jb) = vh;
        }
    }
    __syncthreads();
}

// (512,2): VGPR cap 128. acc[2][8]=64 VGPR + ca/na/bh/addr ~= 100-115, fits.
// LDS 66KB -> 2 blocks/CU, 16 waves.
__launch_bounds__(512, 2)
__global__ void nerf_fused(const float* __restrict__ origins,
                           const float* __restrict__ dirs,
                           const float* __restrict__ nearp,
                           const float* __restrict__ farp,
                           const float* __restrict__ b0,
                           const float* __restrict__ b1,
                           const float* __restrict__ b2,
                           const float* __restrict__ b3,
                           const _Float16* __restrict__ ws,
                           float* __restrict__ out,
                           int nrays)
{
    extern __shared__ _Float16 sm[];
    _Float16* B = sm;                       // [kg4][st8][64ln][8] = 32768 halfs = 64 KB
    float* headv = (float*)(sm + 32768);    // [2 ray][64 samp][4] f32 = 2 KB

    const int tid  = threadIdx.x;
    const int wv   = tid >> 6;
    const int lane = tid & 63;
    const int ray0 = blockIdx.x * 2;
    const int ray1 = ray0 + 1;
    const int ray1c = (ray1 < nrays) ? ray1 : (nrays - 1);

    const float near = nearp[0];
    const float far  = farp[0];
    const float step = (far - near) * (1.0f / 64.0f);

    const float o0x = origins[ray0*3+0], o0y = origins[ray0*3+1], o0z = origins[ray0*3+2];
    const float d0x = dirs[ray0*3+0],    d0y = dirs[ray0*3+1],    d0z = dirs[ray0*3+2];
    const float o1x = origins[ray1c*3+0], o1y = origins[ray1c*3+1], o1z = origins[ray1c*3+2];
    const float d1x = dirs[ray1c*3+0],    d1y = dirs[ray1c*3+1],    d1z = dirs[ray1c*3+2];

    // ---- PE directly into B-frag layout (K padded 63->64): 2 h8 per thread
#pragma unroll
    for (int half = 0; half < 2; ++half) {
        int b  = tid + half*512;         // = (kg*8+st)*64 + ln
        int ln = b & 63;
        int st = (b >> 6) & 7;
        int rr = st >> 2;                // ray within block
        int sample = (st & 3)*16 + (ln & 15);
        int k0 = (b >> 9)*32 + ((ln >> 4) << 3);
        float mid = (near + (float)sample*step) + (near + (float)(sample+1)*step)*0.5f;
        float cox = rr ? o1x : o0x, coy = rr ? o1y : o0y, coz = rr ? o1z : o0z;
        float cdx = rr ? d1x : d0x, cdy = rr ? d1y : d0y, cdz = rr ? d1z : d0z;
        float c3[3] = { cox + mid*cdx, coy + mid*cdy, coz + mid*cdz };
        h8 vh;
#pragma unroll
        for (int j = 0; j < 8; ++j) {
            int k = k0 + j;
            float v;
            if (k < 3) v = c3[k];
            else if (k < 63) {
                int t = k - 3, l = t/6, r = t%6, d = r%3;
                float a = c3[d] * (float)(1 << l);
                v = (r < 3) ? sinf(a) : cosf(a);
            } else v = 0.0f;
            vh[j] = (_Float16)v;
        }
        ((h8*)B)[b] = vh;
    }
    __syncthreads();

    dense_layer<2>(ws+OFF_W0, b0, B, wv, lane);
    dense_layer<8>(ws+OFF_W1, b1, B, wv, lane);
    dense_layer<8>(ws+OFF_W2, b2, B, wv, lane);

    // ---- head: D[16pad ch][128 samp], K split across 8 waves (kg = wv)
    f4 hacc[8];
    {
        h8 ah = ((const h8*)(ws+OFF_W3))[wv*64 + lane];
        const h8* bp = (const h8*)B;
#pragma unroll
        for (int st = 0; st < 8; ++st) {
            f4 z = (f4){0.f, 0.f, 0.f, 0.f};
            hacc[st] = __builtin_amdgcn_mfma_f32_16x16x32_f16(ah, bp[(wv*8 + st)*64 + lane], z, 0, 0, 0);
        }
    }
    __syncthreads();                       // B reads done -> safe to alias

    f4* part = (f4*)sm;                    // [wv][st8][lane] f4 = 64 KB (B region)
#pragma unroll
    for (int st = 0; st < 8; ++st) part[(wv*8 + st)*64 + lane] = hacc[st];
    __syncthreads();

    {
        int stt = tid >> 6, l = tid & 63;  // all 512 threads: one (stTile, lane) each
        f4 s = part[(0*8 + stt)*64 + l];
#pragma unroll
        for (int w = 1; w < 8; ++w) s += part[(w*8 + stt)*64 + l];
        int q = l >> 4, jl = l & 15;
        if (q == 0) {                      // rows 0..3 = the real 4 channels
            s += *(const f4*)b3;
            ((f4*)headv)[(stt >> 2)*64 + (stt & 3)*16 + jl] = s;  // [ray][sample]
        }
    }
    __syncthreads();

    // ---- compositing: waves 0-1, lane = sample, wave = ray
    if (tid < 128) {
        const int rr = tid >> 6;
        const int p  = tid & 63;
        f4 f = ((const f4*)headv)[rr*64 + p];
        float sigma = fmaxf(f[3], 0.0f);
        float delta = (near + (float)(p + 1)*step) - (near + (float)p*step);
        float alpha = 1.0f - expf(-sigma * delta);
        float om    = 1.0f - alpha;

        float prod = om;
#pragma unroll
        for (int off = 1; off < 64; off <<= 1) {
            float v = __shfl_up(prod, off, 64);
            if (p >= off) prod *= v;
        }
        float T = __shfl_up(prod, 1, 64);
        if (p == 0) T = 1.0f;
        float w = T * alpha;

        float r  = w * (1.0f / (1.0f + expf(-f[0])));
        float g  = w * (1.0f / (1.0f + expf(-f[1])));
        float bb = w * (1.0f / (1.0f + expf(-f[2])));
#pragma unroll
        for (int off = 32; off > 0; off >>= 1) {
            r  += __shfl_down(r,  off, 64);
            g  += __shfl_down(g,  off, 64);
            bb += __shfl_down(bb, off, 64);
        }
        if (p == 0 && ray0 + rr < nrays) {
            out[(ray0 + rr)*3 + 0] = r;
            out[(ray0 + rr)*3 + 1] = g;
            out[(ray0 + rr)*3 + 2] = bb;
        }
    }
}

extern "C" void kernel_launch(void* const* d_in, const int* in_sizes, int n_in,
                              void* d_out, int out_size, void* d_ws, size_t ws_size,
                              hipStream_t stream) {
    const float* origins = (const float*)d_in[0];
    const float* dirs    = (const float*)d_in[1];
    const float* nearp   = (const float*)d_in[2];
    const float* farp    = (const float*)d_in[3];
    const float* W0      = (const float*)d_in[4];
    const float* b0      = (const float*)d_in[5];
    const float* W1      = (const float*)d_in[6];
    const float* b1      = (const float*)d_in[7];
    const float* W2      = (const float*)d_in[8];
    const float* b2      = (const float*)d_in[9];
    const float* W3      = (const float*)d_in[10];
    const float* b3      = (const float*)d_in[11];
    float* out           = (float*)d_out;
    _Float16* ws         = (_Float16*)d_ws;

    const int nrays = in_sizes[0] / 3;
    const int nblk  = (nrays + 1) / 2;

    prep_weights<<<dim3(74), dim3(256), 0, stream>>>(W0, W1, W2, W3, ws);

    const size_t shmem = 32768 * sizeof(_Float16) + 128 * sizeof(f4);   // 66 KiB
    hipFuncSetAttribute(reinterpret_cast<const void*>(nerf_fused),
                        hipFuncAttributeMaxDynamicSharedMemorySize,
                        (int)shmem);
    nerf_fused<<<dim3(nblk), dim3(512), shmem, stream>>>(
        origins, dirs, nearp, farp, b0, b1, b2, b3, ws, out, nrays);
}

// Round 3
// 118.721 us; speedup vs baseline: 1.4691x; 1.1812x over previous
//
#include <hip/hip_runtime.h>
#include <math.h>

typedef _Float16 h8 __attribute__((ext_vector_type(8)));
typedef _Float16 h4 __attribute__((ext_vector_type(4)));
typedef float    f4 __attribute__((ext_vector_type(4)));

#define SAMPLES 64
#define HIDDEN  256

// d_ws layout (units: _Float16). Weights plain f16 (RNE), fragment order:
//   ws[((kg*16 + ct)*64 + ln)*8 + j] = W[kg*32 + ((ln>>4)<<3) + j][ct*16 + (ln&15)]
#define OFF_W0 0            // [2][16][64][8]  = 16384 halfs
#define OFF_W1 16384        // [8][16][64][8]  = 65536
#define OFF_W2 81920
#define OFF_W3 147456       // [8][64][8] = 4096 (W3 cols padded 4->16)

__launch_bounds__(256)
__global__ void prep_weights(const float* __restrict__ W0,
                             const float* __restrict__ W1,
                             const float* __restrict__ W2,
                             const float* __restrict__ W3,
                             _Float16* __restrict__ ws)
{
    const int ln = threadIdx.x & 63;
    const int t  = blockIdx.x * 4 + (threadIdx.x >> 6);   // tile id 0..295
    if (t >= 296) return;

    const float* src; int off, kg, ct, kmax, colmax, wide;
    if (t < 32)       { src=W0; off=OFF_W0; kg=t>>4;        ct=t&15;        kmax=63;  colmax=256; wide=1; }
    else if (t < 160) { int u=t-32;  src=W1; off=OFF_W1; kg=u>>4; ct=u&15; kmax=256; colmax=256; wide=1; }
    else if (t < 288) { int u=t-160; src=W2; off=OFF_W2; kg=u>>4; ct=u&15; kmax=256; colmax=256; wide=1; }
    else              { int u=t-288; src=W3; off=OFF_W3; kg=u;    ct=0;    kmax=256; colmax=4;   wide=0; }

    const int col = ct*16 + (ln & 15);
    const int k0  = kg*32 + ((ln >> 4) << 3);
    h8 vh;
#pragma unroll
    for (int j = 0; j < 8; ++j) {
        int k = k0 + j;
        float v = (k < kmax && col < colmax) ? src[k*colmax + col] : 0.0f;
        vh[j] = (_Float16)v;   // RNE
    }
    int di = wide ? ((kg*16 + ct)*64 + ln) : (kg*64 + ln);
    ((h8*)(ws + off))[di] = vh;
}

// Swapped orientation, TWO rays per block. Wave wv owns channels wv*32..+31
// x 128 samples. acc[2][8] = 64 AGPRs (unified file!) -> arch VGPR must stay
// <= 64 so arch+acc <= 128 -> 4 waves/SIMD (2 blocks/CU). r2 evidence: 68
// arch + 64 acc = 132 -> only 3 waves/SIMD -> 1 block resident, 20% occ.
// Slimming: bias loaded AFTER the kg loop (not live across it); weight
// prefetch chained across layers via ca (no kn temp, no layer-entry stall);
// bh batched 4-at-a-time.
template<int NKG>
__device__ __forceinline__ void dense_layer(const _Float16* __restrict__ W,
                                            const float*    __restrict__ bias,
                                            _Float16* B, int wv, int lane,
                                            h8 (&ca)[2],
                                            const h8* __restrict__ next0,
                                            const h8* __restrict__ next1)
{
    const int q  = lane >> 4;
    const int jl = lane & 15;
    f4 acc[2][8];
#pragma unroll
    for (int cht = 0; cht < 2; ++cht)
#pragma unroll
        for (int st = 0; st < 8; ++st) acc[cht][st] = (f4){0.f, 0.f, 0.f, 0.f};

    const h8* wp = (const h8*)W;
    const h8* bp = (const h8*)B;

#pragma unroll
    for (int kg = 0; kg < NKG; ++kg) {
        h8 na[2];
        if (kg + 1 < NKG) {
#pragma unroll
            for (int cht = 0; cht < 2; ++cht)
                na[cht] = wp[((kg+1)*16 + wv*2 + cht)*64 + lane];
        } else {           // last iter: prefetch NEXT layer's kg0 fragments
            na[0] = *next0;
            na[1] = *next1;
        }
#pragma unroll
        for (int sh = 0; sh < 2; ++sh) {
            h8 bh[4];
#pragma unroll
            for (int s = 0; s < 4; ++s)
                bh[s] = bp[(kg*8 + sh*4 + s)*64 + lane];   // ds_read_b128
#pragma unroll
            for (int s = 0; s < 4; ++s) {
                acc[0][sh*4+s] = __builtin_amdgcn_mfma_f32_16x16x32_f16(ca[0], bh[s], acc[0][sh*4+s], 0, 0, 0);
                acc[1][sh*4+s] = __builtin_amdgcn_mfma_f32_16x16x32_f16(ca[1], bh[s], acc[1][sh*4+s], 0, 0, 0);
            }
        }
        ca[0] = na[0]; ca[1] = na[1];
    }

    // bias only needed now (acc was zero-init): not live across the loop.
    f4 bb0 = ((const f4*)bias)[wv*8 + q];
    f4 bb1 = ((const f4*)bias)[wv*8 + 4 + q];

    __syncthreads();   // all waves done reading before in-place overwrite

    // relu(acc+bias) + f16 round into next layer's B-frag layout.
#pragma unroll
    for (int cht = 0; cht < 2; ++cht) {
        f4 bb = cht ? bb1 : bb0;
        int lnp = jl + 16*(cht*2 + (q >> 1));
        int jb  = (q & 1)*4;
#pragma unroll
        for (int st = 0; st < 8; ++st) {
            h4 vh;
#pragma unroll
            for (int r = 0; r < 4; ++r)
                vh[r] = (_Float16)fmaxf(acc[cht][st][r] + bb[r], 0.0f);
            *(h4*)(B + ((wv*8 + st)*64 + lnp)*8 + jb) = vh;
        }
    }
    __syncthreads();
}

__launch_bounds__(512, 2)
__global__ void nerf_fused(const float* __restrict__ origins,
                           const float* __restrict__ dirs,
                           const float* __restrict__ nearp,
                           const float* __restrict__ farp,
                           const float* __restrict__ b0,
                           const float* __restrict__ b1,
                           const float* __restrict__ b2,
                           const float* __restrict__ b3,
                           const _Float16* __restrict__ ws,
                           float* __restrict__ out,
                           int nrays)
{
    extern __shared__ _Float16 sm[];
    _Float16* B = sm;                       // [kg4][st8][64ln][8] = 32768 halfs = 64 KB
    float* headv = (float*)(sm + 32768);    // [2 ray][64 samp][4] f32 = 2 KB

    const int tid  = threadIdx.x;
    const int wv   = tid >> 6;
    const int lane = tid & 63;
    const int ray0 = blockIdx.x * 2;
    const int ray1 = ray0 + 1;
    const int ray1c = (ray1 < nrays) ? ray1 : (nrays - 1);

    // ---- weight prefetch chain: W0 kg0 issued first, hidden under PE
    const int fi0 = (wv*2 + 0)*64 + lane;
    const int fi1 = (wv*2 + 1)*64 + lane;
    const h8* w0p = (const h8*)(ws + OFF_W0);
    const h8* w1p = (const h8*)(ws + OFF_W1);
    const h8* w2p = (const h8*)(ws + OFF_W2);
    const h8* w3p = (const h8*)(ws + OFF_W3);
    h8 wca[2];
    wca[0] = w0p[fi0];
    wca[1] = w0p[fi1];

    const float near = nearp[0];
    const float far  = farp[0];
    const float step = (far - near) * (1.0f / 64.0f);

    // ---- PE: thread -> (sample sg, 16-feature chunk f). f is wave-uniform.
    // Exact double-angle ladder from accurate base sincos (args |x|<~15);
    // ladder error <= ~5e-5 << f16 rounding. No ocml calls in the hot path.
    {
        const int f  = tid >> 7;          // chunk 0..3 (uniform per wave pair)
        const int sg = tid & 127;         // sample 0..127
        const int rr = sg >> 6;
        const int p  = sg & 63;
        const int st = rr*4 + (p >> 4);
        const int jl = p & 15;
        const int kg = f >> 1;
        const int q0 = (f & 1)*2;

        const float mid = (near + (float)p*step) + (near + (float)(p+1)*step)*0.5f;
        const float ox = origins[ray0*3+0], oy = origins[ray0*3+1], oz = origins[ray0*3+2];
        const float dx = dirs[ray0*3+0],    dy = dirs[ray0*3+1],    dz = dirs[ray0*3+2];
        const float o1x = origins[ray1c*3+0], o1y = origins[ray1c*3+1], o1z = origins[ray1c*3+2];
        const float d1x = dirs[ray1c*3+0],    d1y = dirs[ray1c*3+1],    d1z = dirs[ray1c*3+2];
        float c3[3];
        c3[0] = (rr ? o1x : ox) + mid*(rr ? d1x : dx);
        c3[1] = (rr ? o1y : oy) + mid*(rr ? d1y : dy);
        c3[2] = (rr ? o1z : oz) + mid*(rr ? d1z : dz);

        float ls0 = sinf(c3[0]), lc0 = cosf(c3[0]);
        float ls1 = sinf(c3[1]), lc1 = cosf(c3[1]);
        float ls2 = sinf(c3[2]), lc2 = cosf(c3[2]);
#define DBL() { float t0 = 2.f*ls0*lc0; lc0 = 1.f - 2.f*ls0*ls0; ls0 = t0; \
                float t1 = 2.f*ls1*lc1; lc1 = 1.f - 2.f*ls1*ls1; ls1 = t1; \
                float t2 = 2.f*ls2*lc2; lc2 = 1.f - 2.f*ls2*ls2; ls2 = t2; }
        h8 vh0, vh1;
        if (f == 0) {
            vh0[0]=(_Float16)c3[0]; vh0[1]=(_Float16)c3[1]; vh0[2]=(_Float16)c3[2];
            vh0[3]=(_Float16)ls0;   vh0[4]=(_Float16)ls1;   vh0[5]=(_Float16)ls2;
            vh0[6]=(_Float16)lc0;   vh0[7]=(_Float16)lc1;   vh1[0]=(_Float16)lc2;
            DBL();  // l1
            vh1[1]=(_Float16)ls0; vh1[2]=(_Float16)ls1; vh1[3]=(_Float16)ls2;
            vh1[4]=(_Float16)lc0; vh1[5]=(_Float16)lc1; vh1[6]=(_Float16)lc2;
            DBL();  // l2
            vh1[7]=(_Float16)ls0;
        } else if (f == 1) {
            DBL(); DBL();  // l2
            vh0[0]=(_Float16)ls1; vh0[1]=(_Float16)ls2;
            vh0[2]=(_Float16)lc0; vh0[3]=(_Float16)lc1; vh0[4]=(_Float16)lc2;
            DBL();  // l3
            vh0[5]=(_Float16)ls0; vh0[6]=(_Float16)ls1; vh0[7]=(_Float16)ls2;
            vh1[0]=(_Float16)lc0; vh1[1]=(_Float16)lc1; vh1[2]=(_Float16)lc2;
            DBL();  // l4
            vh1[3]=(_Float16)ls0; vh1[4]=(_Float16)ls1; vh1[5]=(_Float16)ls2;
            vh1[6]=(_Float16)lc0; vh1[7]=(_Float16)lc1;
        } else if (f == 2) {
            DBL(); DBL(); DBL(); DBL();  // l4
            vh0[0]=(_Float16)lc2;
            DBL();  // l5
            vh0[1]=(_Float16)ls0; vh0[2]=(_Float16)ls1; vh0[3]=(_Float16)ls2;
            vh0[4]=(_Float16)lc0; vh0[5]=(_Float16)lc1; vh0[6]=(_Float16)lc2;
            DBL();  // l6
            vh0[7]=(_Float16)ls0; vh1[0]=(_Float16)ls1; vh1[1]=(_Float16)ls2;
            vh1[2]=(_Float16)lc0; vh1[3]=(_Float16)lc1; vh1[4]=(_Float16)lc2;
            DBL();  // l7
            vh1[5]=(_Float16)ls0; vh1[6]=(_Float16)ls1; vh1[7]=(_Float16)ls2;
        } else {
            DBL(); DBL(); DBL(); DBL(); DBL(); DBL(); DBL();  // l7
            vh0[0]=(_Float16)lc0; vh0[1]=(_Float16)lc1; vh0[2]=(_Float16)lc2;
            DBL();  // l8
            vh0[3]=(_Float16)ls0; vh0[4]=(_Float16)ls1; vh0[5]=(_Float16)ls2;
            vh0[6]=(_Float16)lc0; vh0[7]=(_Float16)lc1; vh1[0]=(_Float16)lc2;
            DBL();  // l9
            vh1[1]=(_Float16)ls0; vh1[2]=(_Float16)ls1; vh1[3]=(_Float16)ls2;
            vh1[4]=(_Float16)lc0; vh1[5]=(_Float16)lc1; vh1[6]=(_Float16)lc2;
            vh1[7]=(_Float16)0.0f;
        }
#undef DBL
        ((h8*)B)[(kg*8 + st)*64 + (q0    )*16 + jl] = vh0;
        ((h8*)B)[(kg*8 + st)*64 + (q0 + 1)*16 + jl] = vh1;
    }
    __syncthreads();

    dense_layer<2>(ws+OFF_W0, b0, B, wv, lane, wca, &w1p[fi0], &w1p[fi1]);
    dense_layer<8>(ws+OFF_W1, b1, B, wv, lane, wca, &w2p[fi0], &w2p[fi1]);
    dense_layer<8>(ws+OFF_W2, b2, B, wv, lane, wca,
                   &w3p[wv*64 + lane], &w3p[wv*64 + lane]);

    // ---- head: D[16pad ch][128 samp], K split across 8 waves (kg = wv)
    f4 hacc[8];
    {
        h8 ah = wca[0];                     // W3 frag via the prefetch chain
        const h8* bp = (const h8*)B;
#pragma unroll
        for (int st = 0; st < 8; ++st) {
            f4 z = (f4){0.f, 0.f, 0.f, 0.f};
            hacc[st] = __builtin_amdgcn_mfma_f32_16x16x32_f16(ah, bp[(wv*8 + st)*64 + lane], z, 0, 0, 0);
        }
    }
    __syncthreads();                       // B reads done -> safe to alias

    f4* part = (f4*)sm;                    // [wv][st8][lane] f4 = 64 KB (B region)
#pragma unroll
    for (int st = 0; st < 8; ++st) part[(wv*8 + st)*64 + lane] = hacc[st];
    __syncthreads();

    {
        int stt = tid >> 6, l = tid & 63;
        f4 s = part[(0*8 + stt)*64 + l];
#pragma unroll
        for (int w = 1; w < 8; ++w) s += part[(w*8 + stt)*64 + l];
        int q = l >> 4, jl = l & 15;
        if (q == 0) {                      // rows 0..3 = the real 4 channels
            s += *(const f4*)b3;
            ((f4*)headv)[(stt >> 2)*64 + (stt & 3)*16 + jl] = s;  // [ray][sample]
        }
    }
    __syncthreads();

    // ---- compositing: waves 0-1, lane = sample, wave = ray
    if (tid < 128) {
        const int rr = tid >> 6;
        const int p  = tid & 63;
        f4 f = ((const f4*)headv)[rr*64 + p];
        float sigma = fmaxf(f[3], 0.0f);
        float delta = (near + (float)(p + 1)*step) - (near + (float)p*step);
        float alpha = 1.0f - expf(-sigma * delta);
        float om    = 1.0f - alpha;

        float prod = om;
#pragma unroll
        for (int off = 1; off < 64; off <<= 1) {
            float v = __shfl_up(prod, off, 64);
            if (p >= off) prod *= v;
        }
        float T = __shfl_up(prod, 1, 64);
        if (p == 0) T = 1.0f;
        float w = T * alpha;

        float r  = w * (1.0f / (1.0f + expf(-f[0])));
        float g  = w * (1.0f / (1.0f + expf(-f[1])));
        float bb = w * (1.0f / (1.0f + expf(-f[2])));
#pragma unroll
        for (int off = 32; off > 0; off >>= 1) {
            r  += __shfl_down(r,  off, 64);
            g  += __shfl_down(g,  off, 64);
            bb += __shfl_down(bb, off, 64);
        }
        if (p == 0 && ray0 + rr < nrays) {
            out[(ray0 + rr)*3 + 0] = r;
            out[(ray0 + rr)*3 + 1] = g;
            out[(ray0 + rr)*3 + 2] = bb;
        }
    }
}

extern "C" void kernel_launch(void* const* d_in, const int* in_sizes, int n_in,
                              void* d_out, int out_size, void* d_ws, size_t ws_size,
                              hipStream_t stream) {
    const float* origins = (const float*)d_in[0];
    const float* dirs    = (const float*)d_in[1];
    const float* nearp   = (const float*)d_in[2];
    const float* farp    = (const float*)d_in[3];
    const float* W0      = (const float*)d_in[4];
    const float* b0      = (const float*)d_in[5];
    const float* W1      = (const float*)d_in[6];
    const float* b1      = (const float*)d_in[7];
    const float* W2      = (const float*)d_in[8];
    const float* b2      = (const float*)d_in[9];
    const float* W3      = (const float*)d_in[10];
    const float* b3      = (const float*)d_in[11];
    float* out           = (float*)d_out;
    _Float16* ws         = (_Float16*)d_ws;

    const int nrays = in_sizes[0] / 3;
    const int nblk  = (nrays + 1) / 2;

    prep_weights<<<dim3(74), dim3(256), 0, stream>>>(W0, W1, W2, W3, ws);

    const size_t shmem = 32768 * sizeof(_Float16) + 128 * sizeof(f4);   // 66 KiB
    hipFuncSetAttribute(reinterpret_cast<const void*>(nerf_fused),
                        hipFuncAttributeMaxDynamicSharedMemorySize,
                        (int)shmem);
    nerf_fused<<<dim3(nblk), dim3(512), shmem, stream>>>(
        origins, dirs, nearp, farp, b0, b1, b2, b3, ws, out, nrays);
}

// Round 6
// 118.688 us; speedup vs baseline: 1.4695x; 1.0003x over previous
//
#include <hip/hip_runtime.h>
#include <math.h>

typedef _Float16 h8 __attribute__((ext_vector_type(8)));
typedef _Float16 h4 __attribute__((ext_vector_type(4)));
typedef float    f4 __attribute__((ext_vector_type(4)));

#define SAMPLES 64
#define HIDDEN  256

// d_ws layout (units: _Float16). Weights plain f16 (RNE), fragment order:
//   ws[((kg*16 + ct)*64 + ln)*8 + j] = W[kg*32 + ((ln>>4)<<3) + j][ct*16 + (ln&15)]
#define OFF_W0 0            // [2][16][64][8]  = 16384 halfs
#define OFF_W1 16384        // [8][16][64][8]  = 65536
#define OFF_W2 81920
#define OFF_W3 147456       // [8][64][8] = 4096 (W3 cols padded 4->16)

__launch_bounds__(256)
__global__ void prep_weights(const float* __restrict__ W0,
                             const float* __restrict__ W1,
                             const float* __restrict__ W2,
                             const float* __restrict__ W3,
                             _Float16* __restrict__ ws)
{
    const int ln = threadIdx.x & 63;
    const int t  = blockIdx.x * 4 + (threadIdx.x >> 6);   // tile id 0..295
    if (t >= 296) return;

    const float* src; int off, kg, ct, kmax, colmax, wide;
    if (t < 32)       { src=W0; off=OFF_W0; kg=t>>4;        ct=t&15;        kmax=63;  colmax=256; wide=1; }
    else if (t < 160) { int u=t-32;  src=W1; off=OFF_W1; kg=u>>4; ct=u&15; kmax=256; colmax=256; wide=1; }
    else if (t < 288) { int u=t-160; src=W2; off=OFF_W2; kg=u>>4; ct=u&15; kmax=256; colmax=256; wide=1; }
    else              { int u=t-288; src=W3; off=OFF_W3; kg=u;    ct=0;    kmax=256; colmax=4;   wide=0; }

    const int col = ct*16 + (ln & 15);
    const int k0  = kg*32 + ((ln >> 4) << 3);
    h8 vh;
#pragma unroll
    for (int j = 0; j < 8; ++j) {
        int k = k0 + j;
        float v = (k < kmax && col < colmax) ? src[k*colmax + col] : 0.0f;
        vh[j] = (_Float16)v;   // RNE
    }
    int di = wide ? ((kg*16 + ct)*64 + ln) : (kg*64 + ln);
    ((h8*)(ws + off))[di] = vh;
}

// Swapped orientation, TWO rays per block. Wave wv owns channels wv*32..+31
// x 128 samples. acc[2][8] = 64 AGPRs (unified file) -> arch VGPR must stay
// <= 64 so arch+acc <= 128 -> 4 waves/SIMD (2 blocks/CU resident).
// r2/r3 evidence: 68/72 arch + 64 acc > 128 -> 3 waves/SIMD -> 1 block/CU,
// OccupancyPercent ~20, all pipes ~31% (latency-bound).
// R4/R5 WARNING: both slimming attempts (bh[2] batching, waves_per_eu cap,
// index-prefetch) produced WRONG RESULTS despite semantically-identical
// restructures -- unexplained, possibly miscompile. This is the byte-exact
// R3 source (measured 49.5us fused, absmax 6.1e-5). Do not re-apply those
// edits without a correctness explanation.
template<int NKG>
__device__ __forceinline__ void dense_layer(const _Float16* __restrict__ W,
                                            const float*    __restrict__ bias,
                                            _Float16* B, int wv, int lane,
                                            h8 (&ca)[2],
                                            const h8* __restrict__ next0,
                                            const h8* __restrict__ next1)
{
    const int q  = lane >> 4;
    const int jl = lane & 15;
    f4 acc[2][8];
#pragma unroll
    for (int cht = 0; cht < 2; ++cht)
#pragma unroll
        for (int st = 0; st < 8; ++st) acc[cht][st] = (f4){0.f, 0.f, 0.f, 0.f};

    const h8* wp = (const h8*)W;
    const h8* bp = (const h8*)B;

#pragma unroll
    for (int kg = 0; kg < NKG; ++kg) {
        h8 na[2];
        if (kg + 1 < NKG) {
#pragma unroll
            for (int cht = 0; cht < 2; ++cht)
                na[cht] = wp[((kg+1)*16 + wv*2 + cht)*64 + lane];
        } else {           // last iter: prefetch NEXT layer's kg0 fragments
            na[0] = *next0;
            na[1] = *next1;
        }
#pragma unroll
        for (int sh = 0; sh < 2; ++sh) {
            h8 bh[4];
#pragma unroll
            for (int s = 0; s < 4; ++s)
                bh[s] = bp[(kg*8 + sh*4 + s)*64 + lane];   // ds_read_b128
#pragma unroll
            for (int s = 0; s < 4; ++s) {
                acc[0][sh*4+s] = __builtin_amdgcn_mfma_f32_16x16x32_f16(ca[0], bh[s], acc[0][sh*4+s], 0, 0, 0);
                acc[1][sh*4+s] = __builtin_amdgcn_mfma_f32_16x16x32_f16(ca[1], bh[s], acc[1][sh*4+s], 0, 0, 0);
            }
        }
        ca[0] = na[0]; ca[1] = na[1];
    }

    // bias only needed now (acc was zero-init): not live across the loop.
    f4 bb0 = ((const f4*)bias)[wv*8 + q];
    f4 bb1 = ((const f4*)bias)[wv*8 + 4 + q];

    __syncthreads();   // all waves done reading before in-place overwrite

    // relu(acc+bias) + f16 round into next layer's B-frag layout.
#pragma unroll
    for (int cht = 0; cht < 2; ++cht) {
        f4 bb = cht ? bb1 : bb0;
        int lnp = jl + 16*(cht*2 + (q >> 1));
        int jb  = (q & 1)*4;
#pragma unroll
        for (int st = 0; st < 8; ++st) {
            h4 vh;
#pragma unroll
            for (int r = 0; r < 4; ++r)
                vh[r] = (_Float16)fmaxf(acc[cht][st][r] + bb[r], 0.0f);
            *(h4*)(B + ((wv*8 + st)*64 + lnp)*8 + jb) = vh;
        }
    }
    __syncthreads();
}

__launch_bounds__(512, 2)
__global__ void nerf_fused(const float* __restrict__ origins,
                           const float* __restrict__ dirs,
                           const float* __restrict__ nearp,
                           const float* __restrict__ farp,
                           const float* __restrict__ b0,
                           const float* __restrict__ b1,
                           const float* __restrict__ b2,
                           const float* __restrict__ b3,
                           const _Float16* __restrict__ ws,
                           float* __restrict__ out,
                           int nrays)
{
    extern __shared__ _Float16 sm[];
    _Float16* B = sm;                       // [kg4][st8][64ln][8] = 32768 halfs = 64 KB
    float* headv = (float*)(sm + 32768);    // [2 ray][64 samp][4] f32 = 2 KB

    const int tid  = threadIdx.x;
    const int wv   = tid >> 6;
    const int lane = tid & 63;
    const int ray0 = blockIdx.x * 2;
    const int ray1 = ray0 + 1;
    const int ray1c = (ray1 < nrays) ? ray1 : (nrays - 1);

    // ---- weight prefetch chain: W0 kg0 issued first, hidden under PE
    const int fi0 = (wv*2 + 0)*64 + lane;
    const int fi1 = (wv*2 + 1)*64 + lane;
    const h8* w0p = (const h8*)(ws + OFF_W0);
    const h8* w1p = (const h8*)(ws + OFF_W1);
    const h8* w2p = (const h8*)(ws + OFF_W2);
    const h8* w3p = (const h8*)(ws + OFF_W3);
    h8 wca[2];
    wca[0] = w0p[fi0];
    wca[1] = w0p[fi1];

    const float near = nearp[0];
    const float far  = farp[0];
    const float step = (far - near) * (1.0f / 64.0f);

    // ---- PE: thread -> (sample sg, 16-feature chunk f). f is wave-uniform.
    // Exact double-angle ladder from accurate base sincos (args |x|<~15);
    // ladder error <= ~5e-5 << f16 rounding. No ocml calls in the hot path.
    {
        const int f  = tid >> 7;          // chunk 0..3 (uniform per wave pair)
        const int sg = tid & 127;         // sample 0..127
        const int rr = sg >> 6;
        const int p  = sg & 63;
        const int st = rr*4 + (p >> 4);
        const int jl = p & 15;
        const int kg = f >> 1;
        const int q0 = (f & 1)*2;

        const float mid = (near + (float)p*step) + (near + (float)(p+1)*step)*0.5f;
        const float ox = origins[ray0*3+0], oy = origins[ray0*3+1], oz = origins[ray0*3+2];
        const float dx = dirs[ray0*3+0],    dy = dirs[ray0*3+1],    dz = dirs[ray0*3+2];
        const float o1x = origins[ray1c*3+0], o1y = origins[ray1c*3+1], o1z = origins[ray1c*3+2];
        const float d1x = dirs[ray1c*3+0],    d1y = dirs[ray1c*3+1],    d1z = dirs[ray1c*3+2];
        float c3[3];
        c3[0] = (rr ? o1x : ox) + mid*(rr ? d1x : dx);
        c3[1] = (rr ? o1y : oy) + mid*(rr ? d1y : dy);
        c3[2] = (rr ? o1z : oz) + mid*(rr ? d1z : dz);

        float ls0 = sinf(c3[0]), lc0 = cosf(c3[0]);
        float ls1 = sinf(c3[1]), lc1 = cosf(c3[1]);
        float ls2 = sinf(c3[2]), lc2 = cosf(c3[2]);
#define DBL() { float t0 = 2.f*ls0*lc0; lc0 = 1.f - 2.f*ls0*ls0; ls0 = t0; \
                float t1 = 2.f*ls1*lc1; lc1 = 1.f - 2.f*ls1*ls1; ls1 = t1; \
                float t2 = 2.f*ls2*lc2; lc2 = 1.f - 2.f*ls2*ls2; ls2 = t2; }
        h8 vh0, vh1;
        if (f == 0) {
            vh0[0]=(_Float16)c3[0]; vh0[1]=(_Float16)c3[1]; vh0[2]=(_Float16)c3[2];
            vh0[3]=(_Float16)ls0;   vh0[4]=(_Float16)ls1;   vh0[5]=(_Float16)ls2;
            vh0[6]=(_Float16)lc0;   vh0[7]=(_Float16)lc1;   vh1[0]=(_Float16)lc2;
            DBL();  // l1
            vh1[1]=(_Float16)ls0; vh1[2]=(_Float16)ls1; vh1[3]=(_Float16)ls2;
            vh1[4]=(_Float16)lc0; vh1[5]=(_Float16)lc1; vh1[6]=(_Float16)lc2;
            DBL();  // l2
            vh1[7]=(_Float16)ls0;
        } else if (f == 1) {
            DBL(); DBL();  // l2
            vh0[0]=(_Float16)ls1; vh0[1]=(_Float16)ls2;
            vh0[2]=(_Float16)lc0; vh0[3]=(_Float16)lc1; vh0[4]=(_Float16)lc2;
            DBL();  // l3
            vh0[5]=(_Float16)ls0; vh0[6]=(_Float16)ls1; vh0[7]=(_Float16)ls2;
            vh1[0]=(_Float16)lc0; vh1[1]=(_Float16)lc1; vh1[2]=(_Float16)lc2;
            DBL();  // l4
            vh1[3]=(_Float16)ls0; vh1[4]=(_Float16)ls1; vh1[5]=(_Float16)ls2;
            vh1[6]=(_Float16)lc0; vh1[7]=(_Float16)lc1;
        } else if (f == 2) {
            DBL(); DBL(); DBL(); DBL();  // l4
            vh0[0]=(_Float16)lc2;
            DBL();  // l5
            vh0[1]=(_Float16)ls0; vh0[2]=(_Float16)ls1; vh0[3]=(_Float16)ls2;
            vh0[4]=(_Float16)lc0; vh0[5]=(_Float16)lc1; vh0[6]=(_Float16)lc2;
            DBL();  // l6
            vh0[7]=(_Float16)ls0; vh1[0]=(_Float16)ls1; vh1[1]=(_Float16)ls2;
            vh1[2]=(_Float16)lc0; vh1[3]=(_Float16)lc1; vh1[4]=(_Float16)lc2;
            DBL();  // l7
            vh1[5]=(_Float16)ls0; vh1[6]=(_Float16)ls1; vh1[7]=(_Float16)ls2;
        } else {
            DBL(); DBL(); DBL(); DBL(); DBL(); DBL(); DBL();  // l7
            vh0[0]=(_Float16)lc0; vh0[1]=(_Float16)lc1; vh0[2]=(_Float16)lc2;
            DBL();  // l8
            vh0[3]=(_Float16)ls0; vh0[4]=(_Float16)ls1; vh0[5]=(_Float16)ls2;
            vh0[6]=(_Float16)lc0; vh0[7]=(_Float16)lc1; vh1[0]=(_Float16)lc2;
            DBL();  // l9
            vh1[1]=(_Float16)ls0; vh1[2]=(_Float16)ls1; vh1[3]=(_Float16)ls2;
            vh1[4]=(_Float16)lc0; vh1[5]=(_Float16)lc1; vh1[6]=(_Float16)lc2;
            vh1[7]=(_Float16)0.0f;
        }
#undef DBL
        ((h8*)B)[(kg*8 + st)*64 + (q0    )*16 + jl] = vh0;
        ((h8*)B)[(kg*8 + st)*64 + (q0 + 1)*16 + jl] = vh1;
    }
    __syncthreads();

    dense_layer<2>(ws+OFF_W0, b0, B, wv, lane, wca, &w1p[fi0], &w1p[fi1]);
    dense_layer<8>(ws+OFF_W1, b1, B, wv, lane, wca, &w2p[fi0], &w2p[fi1]);
    dense_layer<8>(ws+OFF_W2, b2, B, wv, lane, wca,
                   &w3p[wv*64 + lane], &w3p[wv*64 + lane]);

    // ---- head: D[16pad ch][128 samp], K split across 8 waves (kg = wv)
    f4 hacc[8];
    {
        h8 ah = wca[0];                     // W3 frag via the prefetch chain
        const h8* bp = (const h8*)B;
#pragma unroll
        for (int st = 0; st < 8; ++st) {
            f4 z = (f4){0.f, 0.f, 0.f, 0.f};
            hacc[st] = __builtin_amdgcn_mfma_f32_16x16x32_f16(ah, bp[(wv*8 + st)*64 + lane], z, 0, 0, 0);
        }
    }
    __syncthreads();                       // B reads done -> safe to alias

    f4* part = (f4*)sm;                    // [wv][st8][lane] f4 = 64 KB (B region)
#pragma unroll
    for (int st = 0; st < 8; ++st) part[(wv*8 + st)*64 + lane] = hacc[st];
    __syncthreads();

    {
        int stt = tid >> 6, l = tid & 63;
        f4 s = part[(0*8 + stt)*64 + l];
#pragma unroll
        for (int w = 1; w < 8; ++w) s += part[(w*8 + stt)*64 + l];
        int q = l >> 4, jl = l & 15;
        if (q == 0) {                      // rows 0..3 = the real 4 channels
            s += *(const f4*)b3;
            ((f4*)headv)[(stt >> 2)*64 + (stt & 3)*16 + jl] = s;  // [ray][sample]
        }
    }
    __syncthreads();

    // ---- compositing: waves 0-1, lane = sample, wave = ray
    if (tid < 128) {
        const int rr = tid >> 6;
        const int p  = tid & 63;
        f4 f = ((const f4*)headv)[rr*64 + p];
        float sigma = fmaxf(f[3], 0.0f);
        float delta = (near + (float)(p + 1)*step) - (near + (float)p*step);
        float alpha = 1.0f - expf(-sigma * delta);
        float om    = 1.0f - alpha;

        float prod = om;
#pragma unroll
        for (int off = 1; off < 64; off <<= 1) {
            float v = __shfl_up(prod, off, 64);
            if (p >= off) prod *= v;
        }
        float T = __shfl_up(prod, 1, 64);
        if (p == 0) T = 1.0f;
        float w = T * alpha;

        float r  = w * (1.0f / (1.0f + expf(-f[0])));
        float g  = w * (1.0f / (1.0f + expf(-f[1])));
        float bb = w * (1.0f / (1.0f + expf(-f[2])));
#pragma unroll
        for (int off = 32; off > 0; off >>= 1) {
            r  += __shfl_down(r,  off, 64);
            g  += __shfl_down(g,  off, 64);
            bb += __shfl_down(bb, off, 64);
        }
        if (p == 0 && ray0 + rr < nrays) {
            out[(ray0 + rr)*3 + 0] = r;
            out[(ray0 + rr)*3 + 1] = g;
            out[(ray0 + rr)*3 + 2] = bb;
        }
    }
}

extern "C" void kernel_launch(void* const* d_in, const int* in_sizes, int n_in,
                              void* d_out, int out_size, void* d_ws, size_t ws_size,
                              hipStream_t stream) {
    const float* origins = (const float*)d_in[0];
    const float* dirs    = (const float*)d_in[1];
    const float* nearp   = (const float*)d_in[2];
    const float* farp    = (const float*)d_in[3];
    const float* W0      = (const float*)d_in[4];
    const float* b0      = (const float*)d_in[5];
    const float* W1      = (const float*)d_in[6];
    const float* b1      = (const float*)d_in[7];
    const float* W2      = (const float*)d_in[8];
    const float* b2      = (const float*)d_in[9];
    const float* W3      = (const float*)d_in[10];
    const float* b3      = (const float*)d_in[11];
    float* out           = (float*)d_out;
    _Float16* ws         = (_Float16*)d_ws;

    const int nrays = in_sizes[0] / 3;
    const int nblk  = (nrays + 1) / 2;

    prep_weights<<<dim3(74), dim3(256), 0, stream>>>(W0, W1, W2, W3, ws);

    const size_t shmem = 32768 * sizeof(_Float16) + 128 * sizeof(f4);   // 66 KiB
    hipFuncSetAttribute(reinterpret_cast<const void*>(nerf_fused),
                        hipFuncAttributeMaxDynamicSharedMemorySize,
                        (int)shmem);
    nerf_fused<<<dim3(nblk), dim3(512), shmem, stream>>>(
        origins, dirs, nearp, farp, b0, b1, b2, b3, ws, out, nrays);
}